// Round 7
// baseline (2833.403 us; speedup 1.0000x reference)
//
#include <hip/hip_runtime.h>

#define L_SZ 2048
#define DIM_SZ 512
#define SPADK 1088   // 513 re + 513 im + 62 zero pad (multiple of 32)

// ---------------- per-batch LoRA factor GEMVs: out[b*rows + r] = dot(mat[r], g[b]) ----
__global__ __launch_bounds__(256) void lora_vec_k(const float* __restrict__ mat, int rows,
                                                  const float* __restrict__ g,
                                                  float* __restrict__ out) {
  __shared__ float gs[2048];
  int tid = threadIdx.x;
#pragma unroll
  for (int i = 0; i < 8; i++) gs[i * 256 + tid] = g[i * 256 + tid];
  __syncthreads();
  int row = blockIdx.x * 4 + (tid >> 6);
  if (row >= rows) return;
  int lane = tid & 63;
  float4 mv = *(const float4*)(mat + (size_t)row * 256 + lane * 4);
  float p[8];
#pragma unroll
  for (int b = 0; b < 8; b++) {
    const float* gb = gs + b * 256 + lane * 4;
    p[b] = mv.x * gb[0] + mv.y * gb[1] + mv.z * gb[2] + mv.w * gb[3];
  }
#pragma unroll
  for (int b = 0; b < 8; b++) {
    float v = p[b];
#pragma unroll
    for (int off = 32; off > 0; off >>= 1) v += __shfl_down(v, off, 64);
    if (lane == 0) out[(size_t)b * rows + row] = v;
  }
}

// ------- W_eff[b][m][k] = W[m][k] + sum_r aout[b][r*M+m] * ain[b][k*R+r]  (fp32) -------
__global__ __launch_bounds__(256) void weff_k(const float* __restrict__ W,
                                              const float* __restrict__ ain,
                                              const float* __restrict__ aout,
                                              float* __restrict__ out, int M, int Mpad,
                                              int K, int R) {
  int b = blockIdx.z;
  size_t flat = (size_t)blockIdx.x * 256 + threadIdx.x;  // over Mpad*K (exact multiple)
  int m = (int)(flat / K), k = (int)(flat % K);
  float v = 0.f;
  if (m < M) {
    v = W[(size_t)m * K + k];
    const float* ai = ain + ((size_t)b * K + k) * R;
    const float* ao = aout + (size_t)b * M * R + m;
    for (int r = 0; r < R; r++) v += ai[r] * ao[(size_t)r * M];
  }
  out[((size_t)b * Mpad + m) * K + k] = v;
}

// -------- causal depthwise conv: h0[b][t][c] = sum_k w[c][k] * x[b][c][t-k]  (fp32) ----
__global__ __launch_bounds__(256) void dconv_k(const float* __restrict__ x,
                                               const float* __restrict__ w,
                                               const float* __restrict__ bias,
                                               float* __restrict__ h0) {
  const int t0 = blockIdx.x * 64;
  const int c0 = blockIdx.y * 64;
  const int b = blockIdx.z;
  const int tid = threadIdx.x;
  __shared__ float xs[64 * 68];
  const float* xb = x + ((size_t)b * DIM_SZ + c0) * L_SZ;
#pragma unroll
  for (int i = 0; i < 17; i++) {
    int flat = i * 256 + tid;  // 0..4351 = 64*68
    int c = flat / 68, tt = flat % 68;
    int t = t0 - 4 + tt;
    xs[c * 68 + tt] = (t >= 0) ? xb[(size_t)c * L_SZ + t] : 0.0f;
  }
  __syncthreads();
  int c = tid & 63;
  int tb = (tid >> 6) * 16;
  float wl[5];
#pragma unroll
  for (int k = 0; k < 5; k++) wl[k] = w[(c0 + c) * 5 + k];
  float bl = bias[c0 + c];
  float* o = h0 + ((size_t)b * L_SZ + t0 + tb) * DIM_SZ + c0 + c;
#pragma unroll
  for (int j = 0; j < 16; j++) {
    int t = tb + j;
    float acc = bl;
#pragma unroll
    for (int k = 0; k < 5; k++) acc += wl[k] * xs[c * 68 + t + 4 - k];
    o[(size_t)j * DIM_SZ] = acc;
  }
}

// ---- istft basis, x1024 scale (window + sideband weights folded), fp32; + win (f64) ---
__global__ __launch_bounds__(256) void atab_k(float* __restrict__ A, double* __restrict__ win) {
  int flat = blockIdx.x * 256 + threadIdx.x;  // over 1024*1088
  int n = flat / SPADK, kk = flat % SPADK;
  const double W = 6.283185307179586476925287 / 1024.0;
  double wn = 0.5 * (1.0 - cos(W * (double)n));
  float val = 0.f;
  if (kk < 513) {
    int k = kk;
    int mm = (k * n) & 1023;
    double wk = (k == 0 || k == 512) ? 1.0 : 2.0;
    val = (float)(wn * wk * cos(W * (double)mm));
  } else if (kk < 1026) {
    int k = kk - 513;
    int mm = (k * n) & 1023;
    val = (float)(-wn * 2.0 * sin(W * (double)mm));
  }
  A[flat] = val;
  if (kk == 0) win[n] = wn;
}

// ------- S prep: read fp32 (m,p) logits row, write S = mag*e^{ip} (fp32) + zero pads ---
__global__ __launch_bounds__(256) void sprep_k(const float* __restrict__ mp,
                                               float* __restrict__ S) {
  size_t flat = (size_t)blockIdx.x * 256 + threadIdx.x;  // over 8*2048*576
  size_t row = flat / 576;
  int k = (int)(flat % 576);
  float* o = S + row * SPADK;
  if (k < 513) {
    const float* r = mp + row * SPADK;
    float m = r[k], p = r[513 + k];
    float mag = fminf(expf(m), 100.0f);
    o[k] = mag * cosf(p);
    o[513 + k] = mag * sinf(p);
  } else if (k < 575) {  // zero pad cols 1026..1087
    o[513 + k] = 0.f;
  }
}

// ---- plain fp32 LDS-tiled GEMM: C[b][t][m] = act( sum_k A[b][m][k]*B[b][t][k] + bias )
template <bool GELU>
__global__ __launch_bounds__(256) void gemm32(const float* __restrict__ A, size_t a_bs,
                                              const float* __restrict__ Bm, size_t b_bs,
                                              const float* __restrict__ bias, int Mb,
                                              float* __restrict__ C, size_t c_bs, int ldc,
                                              int Mst, int K) {
  const int b = blockIdx.z;
  const int m0 = blockIdx.x * 64;
  const int t0 = blockIdx.y * 64;
  const int tid = threadIdx.x;
  __shared__ float As[64][33];
  __shared__ float Bs[64][33];
  const float* Ab = A + (size_t)b * a_bs + (size_t)m0 * K;
  const float* Bb = Bm + (size_t)b * b_bs + (size_t)t0 * K;
  const int tm = tid & 15;   // m-subtile
  const int tt = tid >> 4;   // t-subtile
  float acc[4][4] = {};
  for (int kt = 0; kt < K; kt += 32) {
#pragma unroll
    for (int i = 0; i < 2; i++) {
      int ch = i * 256 + tid;            // 0..511
      int row = ch >> 3, kc = (ch & 7) * 4;
      *(float4*)(&As[row][kc]) = *(const float4*)(Ab + (size_t)row * K + kt + kc);
      *(float4*)(&Bs[row][kc]) = *(const float4*)(Bb + (size_t)row * K + kt + kc);
    }
    __syncthreads();
#pragma unroll 8
    for (int kk = 0; kk < 32; kk++) {
      float am[4], bv[4];
#pragma unroll
      for (int i = 0; i < 4; i++) am[i] = As[tm * 4 + i][kk];
#pragma unroll
      for (int j = 0; j < 4; j++) bv[j] = Bs[tt * 4 + j][kk];
#pragma unroll
      for (int i = 0; i < 4; i++)
#pragma unroll
        for (int j = 0; j < 4; j++) acc[i][j] += am[i] * bv[j];
    }
    __syncthreads();
  }
  if (m0 + tm * 4 >= Mst) return;  // clip padded A rows
#pragma unroll
  for (int j = 0; j < 4; j++) {
    float4 v4;
    float* vp = &v4.x;
#pragma unroll
    for (int i = 0; i < 4; i++) {
      float v = acc[i][j];
      int m = m0 + tm * 4 + i;
      if (bias != nullptr && m < Mb) v += bias[m];
      if (GELU) v = 0.5f * v * (1.0f + erff(v * 0.70710678118654752f));
      vp[i] = v;
    }
    *(float4*)(C + (size_t)b * c_bs + (size_t)(t0 + tt * 4 + j) * ldc + m0 + tm * 4) = v4;
  }
}

// ---- iSTFT GEMM with FP64 ACCUMULATION: frames[b][t][n] = sum_k Atab[n][k]*S[b][t][k]
__global__ __launch_bounds__(256) void gemm64(const float* __restrict__ A,
                                              const float* __restrict__ Bm, size_t b_bs,
                                              float* __restrict__ C, size_t c_bs, int K) {
  const int b = blockIdx.z;
  const int m0 = blockIdx.x * 64;
  const int t0 = blockIdx.y * 64;
  const int tid = threadIdx.x;
  __shared__ float As[64][33];
  __shared__ float Bs[64][33];
  const float* Ab = A + (size_t)m0 * K;
  const float* Bb = Bm + (size_t)b * b_bs + (size_t)t0 * K;
  const int tm = tid & 15;
  const int tt = tid >> 4;
  double acc[4][4] = {};
  for (int kt = 0; kt < K; kt += 32) {
#pragma unroll
    for (int i = 0; i < 2; i++) {
      int ch = i * 256 + tid;
      int row = ch >> 3, kc = (ch & 7) * 4;
      *(float4*)(&As[row][kc]) = *(const float4*)(Ab + (size_t)row * K + kt + kc);
      *(float4*)(&Bs[row][kc]) = *(const float4*)(Bb + (size_t)row * K + kt + kc);
    }
    __syncthreads();
#pragma unroll 4
    for (int kk = 0; kk < 32; kk++) {
      double am[4], bv[4];
#pragma unroll
      for (int i = 0; i < 4; i++) am[i] = (double)As[tm * 4 + i][kk];
#pragma unroll
      for (int j = 0; j < 4; j++) bv[j] = (double)Bs[tt * 4 + j][kk];
#pragma unroll
      for (int i = 0; i < 4; i++)
#pragma unroll
        for (int j = 0; j < 4; j++) acc[i][j] = fma(am[i], bv[j], acc[i][j]);
    }
    __syncthreads();
  }
#pragma unroll
  for (int j = 0; j < 4; j++) {
    float4 v4;
    float* vp = &v4.x;
#pragma unroll
    for (int i = 0; i < 4; i++) vp[i] = (float)acc[i][j];
    *(float4*)(C + (size_t)b * c_bs + (size_t)(t0 + tt * 4 + j) * 1024 + m0 + tm * 4) = v4;
  }
}

// ------- overlap-add + env normalize + crop. FIXED: frames are ALREADY WINDOWED by the
// basis (Atab folds the Hann window), so the OLA sums them directly — the previous
// version multiplied by w[n] a second time (Σw²·ifft instead of Σw·ifft, a 0.75x bias).
__global__ __launch_bounds__(256) void ola_k(const float* __restrict__ frames,
                                             const double* __restrict__ win,
                                             float* __restrict__ out) {
  size_t flat = (size_t)blockIdx.x * 256 + threadIdx.x;  // over 8*524288
  int b = (int)(flat >> 19);
  int t = (int)(flat & 524287);
  int g = t + 384;  // PAD
  int r = g & 255, q4 = g >> 8;
  double acc = 0.0, env = 0.0;
#pragma unroll
  for (int q = 0; q < 4; q++) {
    int tau = q4 - q;
    int n = r + 256 * q;
    if (tau >= 0 && tau < 2048) {
      double w = win[n];
      acc += (double)frames[((size_t)b * 2048 + tau) * 1024 + n];  // pre-windowed
      env = fma(w, w, env);
    }
  }
  out[flat] = (float)(acc / (env * 1024.0));
}

extern "C" void kernel_launch(void* const* d_in, const int* in_sizes, int n_in, void* d_out,
                              int out_size, void* d_ws, size_t ws_size, hipStream_t stream) {
  (void)in_sizes; (void)n_in; (void)out_size; (void)ws_size;
  const float* x       = (const float*)d_in[0];
  const float* g_out   = (const float*)d_in[1];
  const float* dconv_w = (const float*)d_in[2];
  const float* dconv_b = (const float*)d_in[3];
  const float* p1_w    = (const float*)d_in[4];
  const float* p1_b    = (const float*)d_in[5];
  const float* p1_ain  = (const float*)d_in[6];
  const float* p1_aout = (const float*)d_in[7];
  const float* p2_w    = (const float*)d_in[8];
  const float* p2_b    = (const float*)d_in[9];
  const float* p2_ain  = (const float*)d_in[10];
  const float* p2_aout = (const float*)d_in[11];
  const float* out_w   = (const float*)d_in[12];
  const float* out_b   = (const float*)d_in[13];
  const float* out_ain = (const float*)d_in[14];
  const float* out_aout= (const float*)d_in[15];

  // Workspace (peak ~172.5 MB < R1-proven 192.3 MB).
  char* ws = (char*)d_ws;
  float* ain1  = (float*)(ws + 0);
  float* aout1 = (float*)(ws + 196608);
  float* ain2  = (float*)(ws + 786432);
  float* aout2 = (float*)(ws + 1376256);
  float* ain3  = (float*)(ws + 1572864);
  float* aout3 = (float*)(ws + 1835008);
  float* Atab  = (float*)(ws + 2360320);   // 4,456,448 B
  double* win  = (double*)(ws + 6816768);  // 8,192 B
  char*  arena = ws + 6824960;
  // arena slots (fp32), lifetime-disjoint:
  float* weff1 = (float*)(arena + 0);           // 25,165,824  [weff1 .. chunk loop]
  float* weff2 = (float*)(arena + 25165824);    // 25,165,824  [weff2 .. chunk loop]
  float* h1c   = (float*)(arena + 50331648);    // 25,165,824  [per-chunk scratch]
  float* weff3 = (float*)(arena + 75497472);    // 18,874,368  [weff3 .. GEMM3]
  float* h0    = (float*)(arena + 94371840);    // 33,554,432  [dconv .. chunk loop]
  float* h2    = (float*)(arena + 127926272);   // 33,554,432  [chunk loop .. GEMM3]
  float* mp    = (float*)(arena + 0);           // 71,303,168  [GEMM3 .. sprep]
  float* Sb    = (float*)(arena + 94371840);    // 71,303,168  [sprep .. GEMM4]
  float* frames= (float*)(arena + 0);           // 67,108,864  [GEMM4 .. ola]

  lora_vec_k<<<1536, 256, 0, stream>>>(p1_ain, 6144, g_out, ain1);
  lora_vec_k<<<4608, 256, 0, stream>>>(p1_aout, 18432, g_out, aout1);
  lora_vec_k<<<4608, 256, 0, stream>>>(p2_ain, 18432, g_out, ain2);
  lora_vec_k<<<1536, 256, 0, stream>>>(p2_aout, 6144, g_out, aout2);
  lora_vec_k<<<2048, 256, 0, stream>>>(out_ain, 8192, g_out, ain3);
  lora_vec_k<<<4104, 256, 0, stream>>>(out_aout, 16416, g_out, aout3);
  atab_k<<<4352, 256, 0, stream>>>(Atab, win);
  dconv_k<<<dim3(32, 8, 8), 256, 0, stream>>>(x, dconv_w, dconv_b, h0);
  weff_k<<<dim3(3072, 1, 8), 256, 0, stream>>>(p1_w, ain1, aout1, weff1, 1536, 1536, 512, 12);
  weff_k<<<dim3(3072, 1, 8), 256, 0, stream>>>(p2_w, ain2, aout2, weff2, 512, 512, 1536, 12);

  // layers 1+2 in 4 time-chunks of 512 through h1c
  for (int c = 0; c < 4; c++) {
    const float* h0c = h0 + (size_t)c * 512 * 512;
    float* h2c = h2 + (size_t)c * 512 * 512;
    gemm32<true><<<dim3(24, 8, 8), 256, 0, stream>>>(
        weff1, (size_t)1536 * 512, h0c, (size_t)2048 * 512, p1_b, 1536,
        h1c, (size_t)512 * 1536, 1536, 1536, 512);
    gemm32<true><<<dim3(8, 8, 8), 256, 0, stream>>>(
        weff2, (size_t)512 * 1536, h1c, (size_t)512 * 1536, p2_b, 512,
        h2c, (size_t)2048 * 512, 512, 512, 1536);
  }

  weff_k<<<dim3(2304, 1, 8), 256, 0, stream>>>(out_w, ain3, aout3, weff3, 1026, 1152, 512, 16);
  gemm32<false><<<dim3(18, 32, 8), 256, 0, stream>>>(
      weff3, (size_t)1152 * 512, h2, (size_t)2048 * 512, out_b, 1026,
      mp, (size_t)2048 * SPADK, SPADK, SPADK, 512);
  sprep_k<<<36864, 256, 0, stream>>>(mp, Sb);
  gemm64<<<dim3(16, 32, 8), 256, 0, stream>>>(
      Atab, Sb, (size_t)2048 * SPADK, frames, (size_t)2048 * 1024, SPADK);
  ola_k<<<16384, 256, 0, stream>>>(frames, win, (float*)d_out);
}